// Round 1
// baseline (1889.764 us; speedup 1.0000x reference)
//
#include <hip/hip_runtime.h>

// SpectralGatingNetwork: y[b,c] = irfft2(rfft2(x[b,c]) * wc[:, :, c]) (ortho norms cancel)
// B=64, C=768, H=64, W=64, WF=33.
// Strategy: pack batches (2b, 2b+1) of one channel as re/im of one complex 64x64
// field; one complex 2D FFT (radix-8 x radix-8 per axis) in LDS; per-element
// Hermitian split + gate + repack; inverse FFT via conj trick with 1/4096 scale.

struct cplx { float re, im; };
__device__ __forceinline__ cplx cadd(cplx a, cplx b){ return {a.re+b.re, a.im+b.im}; }
__device__ __forceinline__ cplx csub(cplx a, cplx b){ return {a.re-b.re, a.im-b.im}; }
__device__ __forceinline__ cplx cmul(cplx a, cplx b){ return {a.re*b.re - a.im*b.im, a.re*b.im + a.im*b.re}; }
__device__ __forceinline__ cplx cnegi(cplx a){ return {a.im, -a.re}; }  // a * (-i)

// In-place forward DFT-8, natural order in/out.
__device__ __forceinline__ void dft8(cplx* u) {
  cplx e0=u[0], e1=u[2], e2=u[4], e3=u[6];
  cplx o0=u[1], o1=u[3], o2=u[5], o3=u[7];
  // DFT4 of evens
  cplx t0=cadd(e0,e2), t1=csub(e0,e2), t2=cadd(e1,e3), t3=cnegi(csub(e1,e3));
  cplx E0=cadd(t0,t2), E2=csub(t0,t2), E1=cadd(t1,t3), E3=csub(t1,t3);
  // DFT4 of odds
  t0=cadd(o0,o2); t1=csub(o0,o2); t2=cadd(o1,o3); t3=cnegi(csub(o1,o3));
  cplx O0=cadd(t0,t2), O2=csub(t0,t2), O1=cadd(t1,t3), O3=csub(t1,t3);
  const float s = 0.70710678118654752440f;
  cplx W1 = { s*(O1.re + O1.im), s*(O1.im - O1.re) };   // O1 * w8^1
  cplx W2 = cnegi(O2);                                   // O2 * w8^2
  cplx W3 = { s*(O3.im - O3.re), -s*(O3.re + O3.im) };   // O3 * w8^3
  u[0]=cadd(E0,O0); u[4]=csub(E0,O0);
  u[1]=cadd(E1,W1); u[5]=csub(E1,W1);
  u[2]=cadd(E2,W2); u[6]=csub(E2,W2);
  u[3]=cadd(E3,W3); u[7]=csub(E3,W3);
}

// One length-64 forward FFT along an axis of the 64x64 complex LDS array.
// COL=false: transform along w (LDS offset r*65 + n); COL=true: along h (n*65 + r).
// Thread mapping r=t&63, second index t>>6 (+4) keeps every LDS access at
// exactly 2 lanes/bank (free on CDNA4).
template<bool COL>
__device__ __forceinline__ void fft_pass(float* zre, float* zim,
                                         const float* twr, const float* twi, int t) {
  const int r  = t & 63;
  const int i0 = t >> 6;
  cplx u[2][8];
  // ---- stage 1: X partial: DFT8 over a of x[8a+b], then twiddle w64^{b*c} ----
  #pragma unroll
  for (int ii=0; ii<2; ++ii) {
    const int b = i0 + 4*ii;
    #pragma unroll
    for (int a=0; a<8; ++a) {
      const int n = 8*a + b;
      const int o = COL ? n*65 + r : r*65 + n;
      u[ii][a].re = zre[o]; u[ii][a].im = zim[o];
    }
    dft8(u[ii]);
    #pragma unroll
    for (int k=1; k<8; ++k) {            // b*k <= 49 < 64
      cplx w = { twr[b*k], twi[b*k] };
      u[ii][k] = cmul(u[ii][k], w);
    }
  }
  __syncthreads();
  #pragma unroll
  for (int ii=0; ii<2; ++ii) {
    const int b = i0 + 4*ii;
    #pragma unroll
    for (int k=0; k<8; ++k) {
      const int n = 8*b + k;
      const int o = COL ? n*65 + r : r*65 + n;
      zre[o] = u[ii][k].re; zim[o] = u[ii][k].im;
    }
  }
  __syncthreads();
  // ---- stage 2: DFT8 over b, scatter to natural order c+8d ----
  #pragma unroll
  for (int ii=0; ii<2; ++ii) {
    const int c = i0 + 4*ii;
    #pragma unroll
    for (int b=0; b<8; ++b) {
      const int n = 8*b + c;
      const int o = COL ? n*65 + r : r*65 + n;
      u[ii][b].re = zre[o]; u[ii][b].im = zim[o];
    }
    dft8(u[ii]);
  }
  __syncthreads();
  #pragma unroll
  for (int ii=0; ii<2; ++ii) {
    const int c = i0 + 4*ii;
    #pragma unroll
    for (int d=0; d<8; ++d) {
      const int n = c + 8*d;
      const int o = COL ? n*65 + r : r*65 + n;
      zre[o] = u[ii][d].re; zim[o] = u[ii][d].im;
    }
  }
  __syncthreads();
}

__global__ __launch_bounds__(256, 4)
void sgn_kernel(const float* __restrict__ x, const float* __restrict__ wg,
                float* __restrict__ out) {
  __shared__ float zre[64*65];
  __shared__ float zim[64*65];
  __shared__ float twr[64];
  __shared__ float twi[64];

  const int t  = threadIdx.x;
  const int bp = blockIdx.x;   // batch pair 0..31
  const int ch = blockIdx.y;   // channel 0..767
  const int b0 = 2*bp, b1 = 2*bp + 1;
  const float* x1 = x + ((size_t)b0*768 + ch)*4096;
  const float* x2 = x + ((size_t)b1*768 + ch)*4096;

  if (t < 64) {
    float ang = -0.0981747704246810387f * (float)t;   // -2*pi*t/64
    twr[t] = cosf(ang);
    twi[t] = sinf(ang);
  }
  // load: z = x1 + i*x2  (coalesced float4; LDS writes 2 lanes/bank)
  #pragma unroll
  for (int j=0; j<4; ++j) {
    const int f = t + 256*j;                 // float4 index in plane
    float4 a = reinterpret_cast<const float4*>(x1)[f];
    float4 b = reinterpret_cast<const float4*>(x2)[f];
    const int o = (f >> 4)*65 + (f & 15)*4;
    zre[o]=a.x; zre[o+1]=a.y; zre[o+2]=a.z; zre[o+3]=a.w;
    zim[o]=b.x; zim[o+1]=b.y; zim[o+2]=b.z; zim[o+3]=b.w;
  }
  __syncthreads();

  fft_pass<false>(zre, zim, twr, twi, t);   // FFT along w
  fft_pass<true >(zre, zim, twr, twi, t);   // FFT along h  -> Z = FFT2(z)

  // gate: split packed spectra, multiply by (Hermitian-consistent) gate,
  // repack as conj(P1 + i*P2)/4096 so a *forward* FFT2 gives the inverse.
  cplx res[16];
  #pragma unroll
  for (int j=0; j<16; ++j) {
    const int flat = t + 256*j;
    const int h = flat >> 6, w = flat & 63;
    const int hb = (64 - h) & 63, wb = (64 - w) & 63;
    cplx Zc = { zre[h*65 + w],   zim[h*65 + w]   };
    cplx Zs = { zre[hb*65 + wb], zim[hb*65 + wb] };
    cplx X1 = { 0.5f*(Zc.re + Zs.re), 0.5f*(Zc.im - Zs.im) };
    cplx X2 = { 0.5f*(Zc.im + Zs.im), 0.5f*(Zs.re - Zc.re) };
    float wr, wi;
    if (w < 33) {
      const float* p = wg + (((size_t)h*33 + w)*768 + ch)*2;
      wr = p[0]; wi = p[1];
      if (w == 0 || w == 32) {
        // irfft2 drops the anti-Hermitian part of these columns ->
        // symmetrize the gate so packed planes separate exactly.
        const float* q = wg + (((size_t)hb*33 + w)*768 + ch)*2;
        wr = 0.5f*(wr + q[0]); wi = 0.5f*(wi - q[1]);
      }
    } else {
      const float* p = wg + (((size_t)hb*33 + (64 - w))*768 + ch)*2;
      wr = p[0]; wi = -p[1];                 // conj-symmetric extension
    }
    cplx P1 = { X1.re*wr - X1.im*wi, X1.re*wi + X1.im*wr };
    cplx P2 = { X2.re*wr - X2.im*wi, X2.re*wi + X2.im*wr };
    const float sc = 1.0f/4096.0f;           // full 2D inverse scale
    res[j].re =  sc*(P1.re - P2.im);
    res[j].im = -sc*(P1.im + P2.re);
  }
  __syncthreads();
  #pragma unroll
  for (int j=0; j<16; ++j) {
    const int flat = t + 256*j;
    const int h = flat >> 6, w = flat & 63;
    zre[h*65 + w] = res[j].re;
    zim[h*65 + w] = res[j].im;
  }
  __syncthreads();

  fft_pass<false>(zre, zim, twr, twi, t);
  fft_pass<true >(zre, zim, twr, twi, t);   // V = FFT2(conj(Z')/4096)

  // y1 = Re(V), y2 = -Im(V)
  float* o1 = out + ((size_t)b0*768 + ch)*4096;
  float* o2 = out + ((size_t)b1*768 + ch)*4096;
  #pragma unroll
  for (int j=0; j<4; ++j) {
    const int f = t + 256*j;
    const int o = (f >> 4)*65 + (f & 15)*4;
    float4 v1 = {  zre[o],  zre[o+1],  zre[o+2],  zre[o+3] };
    float4 v2 = { -zim[o], -zim[o+1], -zim[o+2], -zim[o+3] };
    reinterpret_cast<float4*>(o1)[f] = v1;
    reinterpret_cast<float4*>(o2)[f] = v2;
  }
}

extern "C" void kernel_launch(void* const* d_in, const int* in_sizes, int n_in,
                              void* d_out, int out_size, void* d_ws, size_t ws_size,
                              hipStream_t stream) {
  const float* x  = (const float*)d_in[0];
  const float* wg = (const float*)d_in[1];
  float* out = (float*)d_out;
  dim3 grid(32, 768);   // bpair fastest -> concurrent blocks share channels (L2 weight reuse)
  sgn_kernel<<<grid, 256, 0, stream>>>(x, wg, out);
}